// Round 1
// baseline (1601.914 us; speedup 1.0000x reference)
//
#include <hip/hip_runtime.h>

#define N_NODES 50000

// ---------------- CSR build: count / scan / fill ----------------

__global__ void count_kernel(const int* __restrict__ dst, int* __restrict__ cnt, int E) {
  int i = blockIdx.x * blockDim.x + threadIdx.x;
  if (i < E) atomicAdd(&cnt[dst[i]], 1);
}

__global__ void __launch_bounds__(1024) scan_kernel(const int* __restrict__ cnt,
    int* __restrict__ row_start, int* __restrict__ row_cur, int n) {
  __shared__ int sums[1024];
  int t = threadIdx.x;
  int CH = (n + 1023) >> 10;              // elements per thread
  int lo = t * CH;
  int hi = min(lo + CH, n);
  int s = 0;
  for (int i = lo; i < hi; ++i) s += cnt[i];
  sums[t] = s;
  __syncthreads();
  // Hillis-Steele inclusive scan over 1024 partials
  for (int off = 1; off < 1024; off <<= 1) {
    int v = (t >= off) ? sums[t - off] : 0;
    __syncthreads();
    sums[t] += v;
    __syncthreads();
  }
  int run = sums[t] - s;                  // exclusive prefix for this chunk
  for (int i = lo; i < hi; ++i) {
    row_start[i] = run;
    row_cur[i] = run;
    run += cnt[i];
  }
}

__global__ void fill_kernel(const int* __restrict__ src, const int* __restrict__ dst,
    int* __restrict__ row_cur, int* __restrict__ src_sorted, int E) {
  int i = blockIdx.x * blockDim.x + threadIdx.x;
  if (i < E) {
    int d = dst[i];
    int pos = atomicAdd(&row_cur[d], 1);
    src_sorted[pos] = src[i];
  }
}

// ---------------- gather-reduce mean aggregation ----------------
// one 64-lane wave per node; lane = feature (or feature pair for d=128)

__global__ void agg_mean64(const float* __restrict__ x, const int* __restrict__ row_start,
    const int* __restrict__ row_cnt, const int* __restrict__ srcs,
    float* __restrict__ agg, int n) {
  int wid = (blockIdx.x * blockDim.x + threadIdx.x) >> 6;
  int lane = threadIdx.x & 63;
  if (wid >= n) return;
  int start = row_start[wid];
  int cnt = row_cnt[wid];
  float acc = 0.f;
  for (int e = 0; e < cnt; ++e) {
    int s = srcs[start + e];
    acc += x[(size_t)s * 64 + lane];
  }
  agg[(size_t)wid * 64 + lane] = acc * (1.0f / (float)max(cnt, 1));
}

__global__ void agg_mean128(const float* __restrict__ h, const int* __restrict__ row_start,
    const int* __restrict__ row_cnt, const int* __restrict__ srcs,
    float* __restrict__ agg, int n) {
  int wid = (blockIdx.x * blockDim.x + threadIdx.x) >> 6;
  int lane = threadIdx.x & 63;
  if (wid >= n) return;
  int start = row_start[wid];
  int cnt = row_cnt[wid];
  float ax = 0.f, ay = 0.f;
  for (int e = 0; e < cnt; ++e) {
    int s = srcs[start + e];
    const float2 v = *(const float2*)(h + (size_t)s * 128 + lane * 2);
    ax += v.x;
    ay += v.y;
  }
  float inv = 1.0f / (float)max(cnt, 1);
  float2 o;
  o.x = ax * inv;
  o.y = ay * inv;
  *(float2*)(agg + (size_t)wid * 128 + lane * 2) = o;
}

// ---------------- fused dual-GEMM + bias + relu ----------------
// out[n, c] = relu( sum_k A[n,k]*Wl[c,k] + B[n,k]*Wr[c,k] + bias[c] )
// block: 64 nodes x 64 cols; thread: 4 nodes x 4 cols; K chunked at 64.
// LDS = 16KB wl + 16KB wr + 16KB a + 16KB b = 64KB exactly.

template<int K>
__global__ void __launch_bounds__(256) sage_gemm(
    const float* __restrict__ A, const float* __restrict__ B,
    const float* __restrict__ Wl, const float* __restrict__ Wr,
    const float* __restrict__ bias, float* __restrict__ outp, int n) {
  constexpr int CT = 64;   // cols per block
  constexpr int TC = 16;   // thread-cols
  constexpr int CQ = 4;    // cols per thread (stride TC)
  constexpr int R  = 4;    // nodes per thread
  constexpr int T  = 64;   // nodes per block
  constexpr int KH = 64;   // K chunk
  constexpr int KH4 = KH / 4;

  __shared__ float4 wl_s[KH4 * CT];   // [k4][c]
  __shared__ float4 wr_s[KH4 * CT];
  __shared__ float4 a_s[T * KH4];     // [node][k4]
  __shared__ float4 b_s[T * KH4];

  const int tid = threadIdx.x;
  const int tc = tid % TC;
  const int tn = tid / TC;            // 0..15
  const int n0 = blockIdx.x * T;
  const int c0 = blockIdx.y * CT;

  float acc[CQ][R];
#pragma unroll
  for (int q = 0; q < CQ; ++q)
#pragma unroll
    for (int r = 0; r < R; ++r) acc[q][r] = 0.f;

  for (int kh = 0; kh < K; kh += KH) {
    if (kh) __syncthreads();
    // stage A/B rows (coalesced f4 loads, row-contiguous LDS stores)
    for (int i = tid; i < T * KH4; i += 256) {
      int nn = i / KH4, k4 = i % KH4;
      int gn = n0 + nn;
      float4 av = make_float4(0.f, 0.f, 0.f, 0.f), bv = av;
      if (gn < n) {
        size_t off = (size_t)gn * K + kh + k4 * 4;
        av = *(const float4*)(A + off);
        bv = *(const float4*)(B + off);
      }
      a_s[nn * KH4 + k4] = av;
      b_s[nn * KH4 + k4] = bv;
    }
    // stage weight tiles, transposed to [k4][c] for contiguous-across-lanes reads
    for (int i = tid; i < CT * KH4; i += 256) {
      int cc = i / KH4, k4 = i % KH4;
      size_t off = (size_t)(c0 + cc) * K + kh + k4 * 4;
      wl_s[k4 * CT + cc] = *(const float4*)(Wl + off);
      wr_s[k4 * CT + cc] = *(const float4*)(Wr + off);
    }
    __syncthreads();
#pragma unroll
    for (int k4 = 0; k4 < KH4; ++k4) {
      float4 wl[CQ], wr[CQ];
#pragma unroll
      for (int q = 0; q < CQ; ++q) {
        wl[q] = wl_s[k4 * CT + tc + q * TC];
        wr[q] = wr_s[k4 * CT + tc + q * TC];
      }
#pragma unroll
      for (int r = 0; r < R; ++r) {
        float4 a = a_s[(tn * R + r) * KH4 + k4];
        float4 b = b_s[(tn * R + r) * KH4 + k4];
#pragma unroll
        for (int q = 0; q < CQ; ++q) {
          acc[q][r] += wl[q].x * a.x + wl[q].y * a.y + wl[q].z * a.z + wl[q].w * a.w
                     + wr[q].x * b.x + wr[q].y * b.y + wr[q].z * b.z + wr[q].w * b.w;
        }
      }
    }
  }
  // epilogue: bias + relu + store
#pragma unroll
  for (int q = 0; q < CQ; ++q) {
    float bv = bias[c0 + tc + q * TC];
#pragma unroll
    for (int r = 0; r < R; ++r) {
      int gn = n0 + tn * R + r;
      if (gn < n) {
        float v = acc[q][r] + bv;
        outp[(size_t)gn * 128 + (c0 + tc + q * TC)] = v > 0.f ? v : 0.f;
      }
    }
  }
}

// ---------------- launch ----------------

extern "C" void kernel_launch(void* const* d_in, const int* in_sizes, int n_in,
                              void* d_out, int out_size, void* d_ws, size_t ws_size,
                              hipStream_t stream) {
  const int N = N_NODES;
  const int E = in_sizes[1] / 2;
  const float* x   = (const float*)d_in[0];
  const int*   src = (const int*)d_in[1];
  const int*   dst = src + E;
  const float* Wl1 = (const float*)d_in[2];
  const float* Wr1 = (const float*)d_in[3];
  const float* b1  = (const float*)d_in[4];
  const float* Wl2 = (const float*)d_in[5];
  const float* Wr2 = (const float*)d_in[6];
  const float* b2  = (const float*)d_in[7];
  float* out = (float*)d_out;

  // workspace layout (~55 MB)
  float* h1   = (float*)d_ws;                    // N*128 f32
  float* aggb = h1 + (size_t)N * 128;            // N*128 f32 (layer1 uses as N*64)
  int* row_cnt    = (int*)(aggb + (size_t)N * 128);
  int* row_start  = row_cnt + N;
  int* row_cur    = row_start + N;
  int* src_sorted = row_cur + N;                 // E ints

  hipMemsetAsync(row_cnt, 0, N * sizeof(int), stream);
  int eb = (E + 255) / 256;
  count_kernel<<<eb, 256, 0, stream>>>(dst, row_cnt, E);
  scan_kernel<<<1, 1024, 0, stream>>>(row_cnt, row_start, row_cur, N);
  fill_kernel<<<eb, 256, 0, stream>>>(src, dst, row_cur, src_sorted, E);

  int ab = (N * 64 + 255) / 256;   // one wave per node, 4 waves/block
  agg_mean64<<<ab, 256, 0, stream>>>(x, row_start, row_cnt, src_sorted, aggb, N);

  dim3 g1((N + 63) / 64, 2);
  sage_gemm<64><<<g1, 256, 0, stream>>>(aggb, x, Wl1, Wr1, b1, h1, N);

  agg_mean128<<<ab, 256, 0, stream>>>(h1, row_start, row_cnt, src_sorted, aggb, N);
  sage_gemm<128><<<g1, 256, 0, stream>>>(aggb, h1, Wl2, Wr2, b2, out, N);
}

// Round 2
// 534.036 us; speedup vs baseline: 2.9996x; 2.9996x over previous
//
#include <hip/hip_runtime.h>

#define N_NODES 50000

// ---------------- CSR build: count / scan / fill ----------------

__global__ void count_kernel(const int* __restrict__ dst, int* __restrict__ cnt, int E) {
  int i = blockIdx.x * blockDim.x + threadIdx.x;
  if (i < E) atomicAdd(&cnt[dst[i]], 1);
}

__global__ void __launch_bounds__(1024) scan_kernel(const int* __restrict__ cnt,
    int* __restrict__ row_start, int* __restrict__ row_cur, int n) {
  __shared__ int sums[1024];
  int t = threadIdx.x;
  int CH = (n + 1023) >> 10;              // elements per thread
  int lo = t * CH;
  int hi = min(lo + CH, n);
  int s = 0;
  for (int i = lo; i < hi; ++i) s += cnt[i];
  sums[t] = s;
  __syncthreads();
  // Hillis-Steele inclusive scan over 1024 partials
  for (int off = 1; off < 1024; off <<= 1) {
    int v = (t >= off) ? sums[t - off] : 0;
    __syncthreads();
    sums[t] += v;
    __syncthreads();
  }
  int run = sums[t] - s;                  // exclusive prefix for this chunk
  for (int i = lo; i < hi; ++i) {
    row_start[i] = run;
    row_cur[i] = run;
    run += cnt[i];
  }
}

__global__ void fill_kernel(const int* __restrict__ src, const int* __restrict__ dst,
    int* __restrict__ row_cur, int* __restrict__ src_sorted, int E) {
  int i = blockIdx.x * blockDim.x + threadIdx.x;
  if (i < E) {
    int d = dst[i];
    int pos = atomicAdd(&row_cur[d], 1);
    src_sorted[pos] = src[i];
  }
}

// ---------------- gather-reduce mean aggregation ----------------
// one 64-lane wave per node; lane = feature (or feature pair for d=128)

__global__ void agg_mean64(const float* __restrict__ x, const int* __restrict__ row_start,
    const int* __restrict__ row_cnt, const int* __restrict__ srcs,
    float* __restrict__ agg, int n) {
  int wid = (blockIdx.x * blockDim.x + threadIdx.x) >> 6;
  int lane = threadIdx.x & 63;
  if (wid >= n) return;
  int start = row_start[wid];
  int cnt = row_cnt[wid];
  float acc = 0.f;
  for (int e = 0; e < cnt; ++e) {
    int s = srcs[start + e];
    acc += x[(size_t)s * 64 + lane];
  }
  agg[(size_t)wid * 64 + lane] = acc * (1.0f / (float)max(cnt, 1));
}

__global__ void agg_mean128(const float* __restrict__ h, const int* __restrict__ row_start,
    const int* __restrict__ row_cnt, const int* __restrict__ srcs,
    float* __restrict__ agg, int n) {
  int wid = (blockIdx.x * blockDim.x + threadIdx.x) >> 6;
  int lane = threadIdx.x & 63;
  if (wid >= n) return;
  int start = row_start[wid];
  int cnt = row_cnt[wid];
  float ax = 0.f, ay = 0.f;
  for (int e = 0; e < cnt; ++e) {
    int s = srcs[start + e];
    const float2 v = *(const float2*)(h + (size_t)s * 128 + lane * 2);
    ax += v.x;
    ay += v.y;
  }
  float inv = 1.0f / (float)max(cnt, 1);
  float2 o;
  o.x = ax * inv;
  o.y = ay * inv;
  *(float2*)(agg + (size_t)wid * 128 + lane * 2) = o;
}

// ---------------- fused dual-GEMM + bias + relu ----------------
// out[n, c] = relu( sum_k A[n,k]*Wl[c,k] + B[n,k]*Wr[c,k] + bias[c] )
// block: 64 nodes x 128 cols (full Dout); thread: 4 nodes x 8 cols; K chunk 32.
// LDS ~51.4 KB -> 3 blocks/CU; #pragma unroll 1 keeps live set ~150 VGPR (no spill).

template<int K>
__global__ void __launch_bounds__(256, 3) sage_gemm(
    const float* __restrict__ A, const float* __restrict__ B,
    const float* __restrict__ Wl, const float* __restrict__ Wr,
    const float* __restrict__ bias, float* __restrict__ outp, int n) {
  constexpr int CT  = 128;       // cols per block (full Dout)
  constexpr int T   = 64;        // nodes per block
  constexpr int KH  = 32;        // K chunk
  constexpr int KH4 = KH / 4;    // 8 f4 per node-row chunk
  constexpr int APAD = KH4 + 1;  // 9 f4 node-row stride (bank-stagger)
  constexpr int WROW = CT + 1;   // 129 f4 k4-row stride (bank-stagger)

  __shared__ float4 wl_s[KH4 * WROW];  // [k4][c]
  __shared__ float4 wr_s[KH4 * WROW];
  __shared__ float4 a_s[T * APAD];     // [node][k4]
  __shared__ float4 b_s[T * APAD];

  const int tid = threadIdx.x;
  const int tc = tid & 15;       // 16 thread-cols, 8 cols each (stride 16)
  const int tn = tid >> 4;       // 16 thread-rows, 4 nodes each
  const int n0 = blockIdx.x * T;

  float acc[8][4];
#pragma unroll
  for (int q = 0; q < 8; ++q)
#pragma unroll
    for (int r = 0; r < 4; ++r) acc[q][r] = 0.f;

  for (int kh = 0; kh < K; kh += KH) {
    if (kh) __syncthreads();
    // stage A/B: 512 f4, coalesced (8 f4 per node row)
#pragma unroll
    for (int p = 0; p < 2; ++p) {
      int i = tid + p * 256;
      int nn = i >> 3, k4 = i & 7;
      int gn = n0 + nn;
      float4 av = make_float4(0.f, 0.f, 0.f, 0.f), bv = av;
      if (gn < n) {
        size_t off = (size_t)gn * K + kh + k4 * 4;
        av = *(const float4*)(A + off);
        bv = *(const float4*)(B + off);
      }
      a_s[nn * APAD + k4] = av;
      b_s[nn * APAD + k4] = bv;
    }
    // stage weights transposed to [k4][c]: 1024 f4 each
#pragma unroll
    for (int p = 0; p < 4; ++p) {
      int i = tid + p * 256;
      int c = i >> 3, k4 = i & 7;
      size_t off = (size_t)c * K + kh + k4 * 4;
      wl_s[k4 * WROW + c] = *(const float4*)(Wl + off);
      wr_s[k4 * WROW + c] = *(const float4*)(Wr + off);
    }
    __syncthreads();
#pragma unroll 1
    for (int k4 = 0; k4 < KH4; ++k4) {
      float4 wl[8], wr[8];
#pragma unroll
      for (int q = 0; q < 8; ++q) {
        wl[q] = wl_s[k4 * WROW + tc + q * 16];
        wr[q] = wr_s[k4 * WROW + tc + q * 16];
      }
#pragma unroll
      for (int r = 0; r < 4; ++r) {
        float4 a = a_s[(tn * 4 + r) * APAD + k4];
        float4 b = b_s[(tn * 4 + r) * APAD + k4];
#pragma unroll
        for (int q = 0; q < 8; ++q) {
          acc[q][r] += wl[q].x * a.x + wl[q].y * a.y + wl[q].z * a.z + wl[q].w * a.w
                     + wr[q].x * b.x + wr[q].y * b.y + wr[q].z * b.z + wr[q].w * b.w;
        }
      }
    }
  }
  // epilogue: bias + relu + store
#pragma unroll
  for (int q = 0; q < 8; ++q) {
    float bv = bias[tc + q * 16];
#pragma unroll
    for (int r = 0; r < 4; ++r) {
      int gn = n0 + tn * 4 + r;
      if (gn < n) {
        float v = acc[q][r] + bv;
        outp[(size_t)gn * 128 + (tc + q * 16)] = v > 0.f ? v : 0.f;
      }
    }
  }
}

// ---------------- launch ----------------

extern "C" void kernel_launch(void* const* d_in, const int* in_sizes, int n_in,
                              void* d_out, int out_size, void* d_ws, size_t ws_size,
                              hipStream_t stream) {
  const int N = N_NODES;
  const int E = in_sizes[1] / 2;
  const float* x   = (const float*)d_in[0];
  const int*   src = (const int*)d_in[1];
  const int*   dst = src + E;
  const float* Wl1 = (const float*)d_in[2];
  const float* Wr1 = (const float*)d_in[3];
  const float* b1  = (const float*)d_in[4];
  const float* Wl2 = (const float*)d_in[5];
  const float* Wr2 = (const float*)d_in[6];
  const float* b2  = (const float*)d_in[7];
  float* out = (float*)d_out;

  // workspace layout (~55 MB)
  float* h1   = (float*)d_ws;                    // N*128 f32
  float* aggb = h1 + (size_t)N * 128;            // N*128 f32 (layer1 uses as N*64)
  int* row_cnt    = (int*)(aggb + (size_t)N * 128);
  int* row_start  = row_cnt + N;
  int* row_cur    = row_start + N;
  int* src_sorted = row_cur + N;                 // E ints

  hipMemsetAsync(row_cnt, 0, N * sizeof(int), stream);
  int eb = (E + 255) / 256;
  count_kernel<<<eb, 256, 0, stream>>>(dst, row_cnt, E);
  scan_kernel<<<1, 1024, 0, stream>>>(row_cnt, row_start, row_cur, N);
  fill_kernel<<<eb, 256, 0, stream>>>(src, dst, row_cur, src_sorted, E);

  int ab = (N * 64 + 255) / 256;   // one wave per node, 4 waves/block
  agg_mean64<<<ab, 256, 0, stream>>>(x, row_start, row_cnt, src_sorted, aggb, N);

  int gb = (N + 63) / 64;
  sage_gemm<64><<<gb, 256, 0, stream>>>(aggb, x, Wl1, Wr1, b1, h1, N);

  agg_mean128<<<ab, 256, 0, stream>>>(h1, row_start, row_cnt, src_sorted, aggb, N);
  sage_gemm<128><<<gb, 256, 0, stream>>>(aggb, h1, Wl2, Wr2, b2, out, N);
}

// Round 3
// 380.010 us; speedup vs baseline: 4.2155x; 1.4053x over previous
//
#include <hip/hip_runtime.h>

#define N_NODES 50000

// ---------------- CSR build: count / hierarchical scan / fill ----------------

__global__ void count_kernel(const int* __restrict__ dst, int* __restrict__ cnt, int E) {
  int i = blockIdx.x * blockDim.x + threadIdx.x;
  if (i < E) atomicAdd(&cnt[dst[i]], 1);
}

// phase 1: per-block (512-elem chunk) sums
__global__ void __launch_bounds__(256) scan_partial(const int* __restrict__ cnt,
    int* __restrict__ partials, int n) {
  int t = threadIdx.x;
  int i0 = blockIdx.x * 512 + t * 2;
  int s = 0;
  if (i0 < n) s += cnt[i0];
  if (i0 + 1 < n) s += cnt[i0 + 1];
  __shared__ int red[4];
#pragma unroll
  for (int off = 32; off; off >>= 1) s += __shfl_down(s, off, 64);
  if ((t & 63) == 0) red[t >> 6] = s;
  __syncthreads();
  if (t == 0) partials[blockIdx.x] = red[0] + red[1] + red[2] + red[3];
}

// phase 2: exclusive scan of block partials (P <= 128), one tiny block
__global__ void __launch_bounds__(128) scan_offsets(int* __restrict__ partials, int P) {
  __shared__ int tmp[128];
  int t = threadIdx.x;
  int v = (t < P) ? partials[t] : 0;
  tmp[t] = v;
  __syncthreads();
#pragma unroll
  for (int off = 1; off < 128; off <<= 1) {
    int u = (t >= off) ? tmp[t - off] : 0;
    __syncthreads();
    tmp[t] += u;
    __syncthreads();
  }
  if (t < P) partials[t] = tmp[t] - v;  // exclusive prefix
}

// phase 3: block-local exclusive scan + global offset -> row_start/row_cur
__global__ void __launch_bounds__(256) scan_apply(const int* __restrict__ cnt,
    const int* __restrict__ partials, int* __restrict__ row_start,
    int* __restrict__ row_cur, int n) {
  __shared__ int tmp[256];
  int t = threadIdx.x;
  int i0 = blockIdx.x * 512 + t * 2;
  int c0 = (i0 < n) ? cnt[i0] : 0;
  int c1 = (i0 + 1 < n) ? cnt[i0 + 1] : 0;
  int s = c0 + c1;
  tmp[t] = s;
  __syncthreads();
#pragma unroll
  for (int off = 1; off < 256; off <<= 1) {
    int u = (t >= off) ? tmp[t - off] : 0;
    __syncthreads();
    tmp[t] += u;
    __syncthreads();
  }
  int ex = tmp[t] - s + partials[blockIdx.x];
  if (i0 < n)     { row_start[i0] = ex;          row_cur[i0] = ex; }
  if (i0 + 1 < n) { row_start[i0 + 1] = ex + c0; row_cur[i0 + 1] = ex + c0; }
}

__global__ void fill_kernel(const int* __restrict__ src, const int* __restrict__ dst,
    int* __restrict__ row_cur, int* __restrict__ src_sorted, int E) {
  int i = blockIdx.x * blockDim.x + threadIdx.x;
  if (i < E) {
    int d = dst[i];
    int pos = atomicAdd(&row_cur[d], 1);
    src_sorted[pos] = src[i];
  }
}

// ---------------- gather-reduce mean aggregation ----------------
// one 64-lane wave per node; lane = feature (or feature pair for d=128)

__global__ void agg_mean64(const float* __restrict__ x, const int* __restrict__ row_start,
    const int* __restrict__ row_cnt, const int* __restrict__ srcs,
    float* __restrict__ agg, int n) {
  int wid = (blockIdx.x * blockDim.x + threadIdx.x) >> 6;
  int lane = threadIdx.x & 63;
  if (wid >= n) return;
  int start = row_start[wid];
  int cnt = row_cnt[wid];
  float a0 = 0.f, a1 = 0.f;
  int e = 0;
  for (; e + 2 <= cnt; e += 2) {
    int s0 = srcs[start + e];
    int s1 = srcs[start + e + 1];
    a0 += x[(size_t)s0 * 64 + lane];
    a1 += x[(size_t)s1 * 64 + lane];
  }
  if (e < cnt) {
    int s0 = srcs[start + e];
    a0 += x[(size_t)s0 * 64 + lane];
  }
  agg[(size_t)wid * 64 + lane] = (a0 + a1) * (1.0f / (float)max(cnt, 1));
}

__global__ void agg_mean128(const float* __restrict__ h, const int* __restrict__ row_start,
    const int* __restrict__ row_cnt, const int* __restrict__ srcs,
    float* __restrict__ agg, int n) {
  int wid = (blockIdx.x * blockDim.x + threadIdx.x) >> 6;
  int lane = threadIdx.x & 63;
  if (wid >= n) return;
  int start = row_start[wid];
  int cnt = row_cnt[wid];
  float ax = 0.f, ay = 0.f, bx = 0.f, by = 0.f;
  int e = 0;
  for (; e + 2 <= cnt; e += 2) {
    int s0 = srcs[start + e];
    int s1 = srcs[start + e + 1];
    const float2 v0 = *(const float2*)(h + (size_t)s0 * 128 + lane * 2);
    const float2 v1 = *(const float2*)(h + (size_t)s1 * 128 + lane * 2);
    ax += v0.x; ay += v0.y;
    bx += v1.x; by += v1.y;
  }
  if (e < cnt) {
    int s0 = srcs[start + e];
    const float2 v0 = *(const float2*)(h + (size_t)s0 * 128 + lane * 2);
    ax += v0.x; ay += v0.y;
  }
  float inv = 1.0f / (float)max(cnt, 1);
  float2 o;
  o.x = (ax + bx) * inv;
  o.y = (ay + by) * inv;
  *(float2*)(agg + (size_t)wid * 128 + lane * 2) = o;
}

// ---------------- fused dual-GEMM + bias + relu ----------------
// out[n, c] = relu( sum_k A[n,k]*Wl[c,k] + B[n,k]*Wr[c,k] + bias[c] )
// block: 64 nodes x 128 cols (full Dout); thread: 4 nodes x 8 cols; K chunk 32.
// LDS ~51.4 KB -> 3 blocks/CU; #pragma unroll 1 keeps live set ~150 VGPR (no spill).

template<int K>
__global__ void __launch_bounds__(256, 3) sage_gemm(
    const float* __restrict__ A, const float* __restrict__ B,
    const float* __restrict__ Wl, const float* __restrict__ Wr,
    const float* __restrict__ bias, float* __restrict__ outp, int n) {
  constexpr int CT  = 128;       // cols per block (full Dout)
  constexpr int T   = 64;        // nodes per block
  constexpr int KH  = 32;        // K chunk
  constexpr int KH4 = KH / 4;    // 8 f4 per node-row chunk
  constexpr int APAD = KH4 + 1;  // 9 f4 node-row stride (bank-stagger)
  constexpr int WROW = CT + 1;   // 129 f4 k4-row stride (bank-stagger)

  __shared__ float4 wl_s[KH4 * WROW];  // [k4][c]
  __shared__ float4 wr_s[KH4 * WROW];
  __shared__ float4 a_s[T * APAD];     // [node][k4]
  __shared__ float4 b_s[T * APAD];

  const int tid = threadIdx.x;
  const int tc = tid & 15;       // 16 thread-cols, 8 cols each (stride 16)
  const int tn = tid >> 4;       // 16 thread-rows, 4 nodes each
  const int n0 = blockIdx.x * T;

  float acc[8][4];
#pragma unroll
  for (int q = 0; q < 8; ++q)
#pragma unroll
    for (int r = 0; r < 4; ++r) acc[q][r] = 0.f;

  for (int kh = 0; kh < K; kh += KH) {
    if (kh) __syncthreads();
    // stage A/B: 512 f4, coalesced (8 f4 per node row)
#pragma unroll
    for (int p = 0; p < 2; ++p) {
      int i = tid + p * 256;
      int nn = i >> 3, k4 = i & 7;
      int gn = n0 + nn;
      float4 av = make_float4(0.f, 0.f, 0.f, 0.f), bv = av;
      if (gn < n) {
        size_t off = (size_t)gn * K + kh + k4 * 4;
        av = *(const float4*)(A + off);
        bv = *(const float4*)(B + off);
      }
      a_s[nn * APAD + k4] = av;
      b_s[nn * APAD + k4] = bv;
    }
    // stage weights transposed to [k4][c]: 1024 f4 each
#pragma unroll
    for (int p = 0; p < 4; ++p) {
      int i = tid + p * 256;
      int c = i >> 3, k4 = i & 7;
      size_t off = (size_t)c * K + kh + k4 * 4;
      wl_s[k4 * WROW + c] = *(const float4*)(Wl + off);
      wr_s[k4 * WROW + c] = *(const float4*)(Wr + off);
    }
    __syncthreads();
#pragma unroll 1
    for (int k4 = 0; k4 < KH4; ++k4) {
      float4 wl[8], wr[8];
#pragma unroll
      for (int q = 0; q < 8; ++q) {
        wl[q] = wl_s[k4 * WROW + tc + q * 16];
        wr[q] = wr_s[k4 * WROW + tc + q * 16];
      }
#pragma unroll
      for (int r = 0; r < 4; ++r) {
        float4 a = a_s[(tn * 4 + r) * APAD + k4];
        float4 b = b_s[(tn * 4 + r) * APAD + k4];
#pragma unroll
        for (int q = 0; q < 8; ++q) {
          acc[q][r] += wl[q].x * a.x + wl[q].y * a.y + wl[q].z * a.z + wl[q].w * a.w
                     + wr[q].x * b.x + wr[q].y * b.y + wr[q].z * b.z + wr[q].w * b.w;
        }
      }
    }
  }
  // epilogue: bias + relu + store
#pragma unroll
  for (int q = 0; q < 8; ++q) {
    float bv = bias[tc + q * 16];
#pragma unroll
    for (int r = 0; r < 4; ++r) {
      int gn = n0 + tn * 4 + r;
      if (gn < n) {
        float v = acc[q][r] + bv;
        outp[(size_t)gn * 128 + (tc + q * 16)] = v > 0.f ? v : 0.f;
      }
    }
  }
}

// ---------------- launch ----------------

extern "C" void kernel_launch(void* const* d_in, const int* in_sizes, int n_in,
                              void* d_out, int out_size, void* d_ws, size_t ws_size,
                              hipStream_t stream) {
  const int N = N_NODES;
  const int E = in_sizes[1] / 2;
  const float* x   = (const float*)d_in[0];
  const int*   src = (const int*)d_in[1];
  const int*   dst = src + E;
  const float* Wl1 = (const float*)d_in[2];
  const float* Wr1 = (const float*)d_in[3];
  const float* b1  = (const float*)d_in[4];
  const float* Wl2 = (const float*)d_in[5];
  const float* Wr2 = (const float*)d_in[6];
  const float* b2  = (const float*)d_in[7];
  float* out = (float*)d_out;

  // workspace layout (~55 MB)
  float* h1   = (float*)d_ws;                    // N*128 f32
  float* aggb = h1 + (size_t)N * 128;            // N*128 f32 (layer1 uses as N*64)
  int* row_cnt    = (int*)(aggb + (size_t)N * 128);
  int* row_start  = row_cnt + N;
  int* row_cur    = row_start + N;
  int* src_sorted = row_cur + N;                 // E ints
  int* partials   = src_sorted + E;              // 128 ints

  const int SB = (N + 511) / 512;                // scan blocks (98)

  hipMemsetAsync(row_cnt, 0, N * sizeof(int), stream);
  int eb = (E + 255) / 256;
  count_kernel<<<eb, 256, 0, stream>>>(dst, row_cnt, E);
  scan_partial<<<SB, 256, 0, stream>>>(row_cnt, partials, N);
  scan_offsets<<<1, 128, 0, stream>>>(partials, SB);
  scan_apply<<<SB, 256, 0, stream>>>(row_cnt, partials, row_start, row_cur, N);
  fill_kernel<<<eb, 256, 0, stream>>>(src, dst, row_cur, src_sorted, E);

  int ab = (N * 64 + 255) / 256;   // one wave per node, 4 waves/block
  agg_mean64<<<ab, 256, 0, stream>>>(x, row_start, row_cnt, src_sorted, aggb, N);

  int gb = (N + 63) / 64;
  sage_gemm<64><<<gb, 256, 0, stream>>>(aggb, x, Wl1, Wr1, b1, h1, N);

  agg_mean128<<<ab, 256, 0, stream>>>(h1, row_start, row_cnt, src_sorted, aggb, N);
  sage_gemm<128><<<gb, 256, 0, stream>>>(aggb, h1, Wl2, Wr2, b2, out, N);
}

// Round 4
// 308.784 us; speedup vs baseline: 5.1878x; 1.2307x over previous
//
#include <hip/hip_runtime.h>

#define N_NODES 50000

typedef __attribute__((ext_vector_type(8))) short short8;
typedef __attribute__((ext_vector_type(4))) float floatx4;

static __device__ __forceinline__ unsigned short f2bf(float f) {
  unsigned int u = __builtin_bit_cast(unsigned int, f);
  u += 0x7fff + ((u >> 16) & 1);          // RNE
  return (unsigned short)(u >> 16);
}
static __device__ __forceinline__ float bf2f(unsigned short s) {
  unsigned int u = ((unsigned int)s) << 16;
  return __builtin_bit_cast(float, u);
}

// ---------------- input casts ----------------

// x [N][64] f32 -> xbf [N][64] bf16 AND A1[n][64+c] (self half of layer-1 A')
__global__ void cast_x(const float* __restrict__ x, unsigned short* __restrict__ xbf,
                       unsigned short* __restrict__ A1, int total) {
  int i = blockIdx.x * blockDim.x + threadIdx.x;
  if (i >= total) return;
  unsigned short b = f2bf(x[i]);
  xbf[i] = b;
  A1[(size_t)(i >> 6) * 128 + 64 + (i & 63)] = b;
}

// build Wcat1 [128][128] = [Wl1|Wr1], Wcat2 [128][256] = [Wl2|Wr2] (bf16)
__global__ void cast_w(const float* __restrict__ Wl1, const float* __restrict__ Wr1,
                       const float* __restrict__ Wl2, const float* __restrict__ Wr2,
                       unsigned short* __restrict__ W1, unsigned short* __restrict__ W2) {
  int t = blockIdx.x * blockDim.x + threadIdx.x;
  if (t < 128 * 128) {
    int c = t >> 7, k = t & 127;
    W1[t] = f2bf(k < 64 ? Wl1[c * 64 + k] : Wr1[c * 64 + k - 64]);
  } else {
    int t2 = t - 128 * 128;
    if (t2 < 128 * 256) {
      int c = t2 >> 8, k = t2 & 255;
      W2[t2] = f2bf(k < 128 ? Wl2[c * 128 + k] : Wr2[c * 128 + k - 128]);
    }
  }
}

// ---------------- CSR build: count / hierarchical scan / fill ----------------

__global__ void count_kernel(const int* __restrict__ dst, int* __restrict__ cnt, int E) {
  int i = blockIdx.x * blockDim.x + threadIdx.x;
  if (i < E) atomicAdd(&cnt[dst[i]], 1);
}

__global__ void __launch_bounds__(256) scan_partial(const int* __restrict__ cnt,
    int* __restrict__ partials, int n) {
  int t = threadIdx.x;
  int i0 = blockIdx.x * 512 + t * 2;
  int s = 0;
  if (i0 < n) s += cnt[i0];
  if (i0 + 1 < n) s += cnt[i0 + 1];
  __shared__ int red[4];
#pragma unroll
  for (int off = 32; off; off >>= 1) s += __shfl_down(s, off, 64);
  if ((t & 63) == 0) red[t >> 6] = s;
  __syncthreads();
  if (t == 0) partials[blockIdx.x] = red[0] + red[1] + red[2] + red[3];
}

__global__ void __launch_bounds__(128) scan_offsets(int* __restrict__ partials, int P) {
  __shared__ int tmp[128];
  int t = threadIdx.x;
  int v = (t < P) ? partials[t] : 0;
  tmp[t] = v;
  __syncthreads();
#pragma unroll
  for (int off = 1; off < 128; off <<= 1) {
    int u = (t >= off) ? tmp[t - off] : 0;
    __syncthreads();
    tmp[t] += u;
    __syncthreads();
  }
  if (t < P) partials[t] = tmp[t] - v;
}

__global__ void __launch_bounds__(256) scan_apply(const int* __restrict__ cnt,
    const int* __restrict__ partials, int* __restrict__ row_start,
    int* __restrict__ row_cur, int n) {
  __shared__ int tmp[256];
  int t = threadIdx.x;
  int i0 = blockIdx.x * 512 + t * 2;
  int c0 = (i0 < n) ? cnt[i0] : 0;
  int c1 = (i0 + 1 < n) ? cnt[i0 + 1] : 0;
  int s = c0 + c1;
  tmp[t] = s;
  __syncthreads();
#pragma unroll
  for (int off = 1; off < 256; off <<= 1) {
    int u = (t >= off) ? tmp[t - off] : 0;
    __syncthreads();
    tmp[t] += u;
    __syncthreads();
  }
  int ex = tmp[t] - s + partials[blockIdx.x];
  if (i0 < n)     { row_start[i0] = ex;          row_cur[i0] = ex; }
  if (i0 + 1 < n) { row_start[i0 + 1] = ex + c0; row_cur[i0 + 1] = ex + c0; }
}

__global__ void fill_kernel(const int* __restrict__ src, const int* __restrict__ dst,
    int* __restrict__ row_cur, int* __restrict__ src_sorted, int E) {
  int i = blockIdx.x * blockDim.x + threadIdx.x;
  if (i < E) {
    int d = dst[i];
    int pos = atomicAdd(&row_cur[d], 1);
    src_sorted[pos] = src[i];
  }
}

// ---------------- gather-reduce mean aggregation (bf16 in/out, fp32 acc) ----------------

// one wave per node; lane = feature; writes A1[n][0..63]
__global__ void agg_mean64(const unsigned short* __restrict__ xbf,
    const int* __restrict__ row_start, const int* __restrict__ row_cnt,
    const int* __restrict__ srcs, unsigned short* __restrict__ A1, int n) {
  int wid = (blockIdx.x * blockDim.x + threadIdx.x) >> 6;
  int lane = threadIdx.x & 63;
  if (wid >= n) return;
  int start = row_start[wid];
  int cnt = row_cnt[wid];
  float a0 = 0.f, a1 = 0.f;
  int e = 0;
  for (; e + 2 <= cnt; e += 2) {
    int s0 = srcs[start + e];
    int s1 = srcs[start + e + 1];
    a0 += bf2f(xbf[(size_t)s0 * 64 + lane]);
    a1 += bf2f(xbf[(size_t)s1 * 64 + lane]);
  }
  if (e < cnt) a0 += bf2f(xbf[(size_t)srcs[start + e] * 64 + lane]);
  A1[(size_t)wid * 128 + lane] = f2bf((a0 + a1) * (1.0f / (float)max(cnt, 1)));
}

// gathers h1 rows from A2[s][128..255], writes A2[n][0..127]; lane owns 2 cols
__global__ void agg_mean128(const unsigned short* __restrict__ A2c,
    const int* __restrict__ row_start, const int* __restrict__ row_cnt,
    const int* __restrict__ srcs, unsigned short* __restrict__ A2w, int n) {
  int wid = (blockIdx.x * blockDim.x + threadIdx.x) >> 6;
  int lane = threadIdx.x & 63;
  if (wid >= n) return;
  int start = row_start[wid];
  int cnt = row_cnt[wid];
  float ax = 0.f, ay = 0.f, bx = 0.f, by = 0.f;
  int e = 0;
  for (; e + 2 <= cnt; e += 2) {
    int s0 = srcs[start + e];
    int s1 = srcs[start + e + 1];
    unsigned int u0 = *(const unsigned int*)(A2c + (size_t)s0 * 256 + 128 + lane * 2);
    unsigned int u1 = *(const unsigned int*)(A2c + (size_t)s1 * 256 + 128 + lane * 2);
    ax += bf2f((unsigned short)u0); ay += bf2f((unsigned short)(u0 >> 16));
    bx += bf2f((unsigned short)u1); by += bf2f((unsigned short)(u1 >> 16));
  }
  if (e < cnt) {
    unsigned int u0 = *(const unsigned int*)(A2c + (size_t)srcs[start + e] * 256 + 128 + lane * 2);
    ax += bf2f((unsigned short)u0); ay += bf2f((unsigned short)(u0 >> 16));
  }
  float inv = 1.0f / (float)max(cnt, 1);
  unsigned int packed = (unsigned int)f2bf((ax + bx) * inv)
                      | ((unsigned int)f2bf((ay + by) * inv) << 16);
  *(unsigned int*)(A2w + (size_t)wid * 256 + lane * 2) = packed;
}

// ---------------- MFMA GEMM: out = relu(A'(n,KP) x W'(128,KP)^T + bias) ----------------
// LDS-free: A-frag / W-frag are 16B row-contiguous loads (16 distinct 64B lines/wave).
// Block = 4 waves x 32 rows x 128 cols. acc = 64 VGPR/thread.

template<int KP, bool BF_OUT>
__global__ void __launch_bounds__(256) mfma_gemm(
    const unsigned short* __restrict__ A, const unsigned short* __restrict__ W,
    const float* __restrict__ bias, unsigned short* __restrict__ outb,
    float* __restrict__ outf, int n, int ostride, int ocol) {
  const int lane = threadIdx.x & 63;
  const int wv = threadIdx.x >> 6;
  const int m = lane & 15;
  const int q = lane >> 4;
  const int r0 = blockIdx.x * 128 + wv * 32;

  floatx4 acc[2][8];
#pragma unroll
  for (int rt = 0; rt < 2; ++rt)
#pragma unroll
    for (int ct = 0; ct < 8; ++ct) acc[rt][ct] = (floatx4){0.f, 0.f, 0.f, 0.f};

  int ra = r0 + m;      if (ra > n - 1) ra = n - 1;
  int rb = r0 + 16 + m; if (rb > n - 1) rb = n - 1;
  const unsigned short* Arow0 = A + (size_t)ra * KP + q * 8;
  const unsigned short* Arow1 = A + (size_t)rb * KP + q * 8;
  const unsigned short* Wrow  = W + (size_t)m * KP + q * 8;

#pragma unroll 1
  for (int kc = 0; kc < KP / 32; ++kc) {
    short8 a0 = *(const short8*)(Arow0 + kc * 32);
    short8 a1 = *(const short8*)(Arow1 + kc * 32);
#pragma unroll
    for (int ct = 0; ct < 8; ++ct) {
      short8 wf = *(const short8*)(Wrow + (size_t)ct * 16 * KP + kc * 32);
      acc[0][ct] = __builtin_amdgcn_mfma_f32_16x16x32_bf16(a0, wf, acc[0][ct], 0, 0, 0);
      acc[1][ct] = __builtin_amdgcn_mfma_f32_16x16x32_bf16(a1, wf, acc[1][ct], 0, 0, 0);
    }
  }

  float bv[8];
#pragma unroll
  for (int ct = 0; ct < 8; ++ct) bv[ct] = bias[ct * 16 + m];

#pragma unroll
  for (int rt = 0; rt < 2; ++rt) {
#pragma unroll
    for (int j = 0; j < 4; ++j) {
      int row = r0 + rt * 16 + q * 4 + j;
      if (row < n) {
#pragma unroll
        for (int ct = 0; ct < 8; ++ct) {
          float v = acc[rt][ct][j] + bv[ct];
          v = v > 0.f ? v : 0.f;
          int col = ct * 16 + m;
          if (BF_OUT) outb[(size_t)row * ostride + ocol + col] = f2bf(v);
          else        outf[(size_t)row * ostride + col] = v;
        }
      }
    }
  }
}

// ---------------- launch ----------------

extern "C" void kernel_launch(void* const* d_in, const int* in_sizes, int n_in,
                              void* d_out, int out_size, void* d_ws, size_t ws_size,
                              hipStream_t stream) {
  const int N = N_NODES;
  const int E = in_sizes[1] / 2;
  const float* x   = (const float*)d_in[0];
  const int*   src = (const int*)d_in[1];
  const int*   dst = src + E;
  const float* Wl1 = (const float*)d_in[2];
  const float* Wr1 = (const float*)d_in[3];
  const float* b1  = (const float*)d_in[4];
  const float* Wl2 = (const float*)d_in[5];
  const float* Wr2 = (const float*)d_in[6];
  const float* b2  = (const float*)d_in[7];
  float* out = (float*)d_out;

  // workspace (bf16 shorts first, 16B-aligned rows; then ints) ~48.7 MB
  unsigned short* A1  = (unsigned short*)d_ws;        // N*128
  unsigned short* A2  = A1 + (size_t)N * 128;         // N*256
  unsigned short* xbf = A2 + (size_t)N * 256;         // N*64
  unsigned short* W1  = xbf + (size_t)N * 64;         // 128*128
  unsigned short* W2  = W1 + 128 * 128;               // 128*256
  int* row_cnt    = (int*)(W2 + 128 * 256);
  int* row_start  = row_cnt + N;
  int* row_cur    = row_start + N;
  int* src_sorted = row_cur + N;                      // E ints
  int* partials   = src_sorted + E;                   // 128 ints

  const int SB = (N + 511) / 512;

  hipMemsetAsync(row_cnt, 0, N * sizeof(int), stream);
  cast_x<<<(N * 64 + 255) / 256, 256, 0, stream>>>(x, xbf, A1, N * 64);
  cast_w<<<(128 * 128 + 128 * 256 + 255) / 256, 256, 0, stream>>>(Wl1, Wr1, Wl2, Wr2, W1, W2);

  int eb = (E + 255) / 256;
  count_kernel<<<eb, 256, 0, stream>>>(dst, row_cnt, E);
  scan_partial<<<SB, 256, 0, stream>>>(row_cnt, partials, N);
  scan_offsets<<<1, 128, 0, stream>>>(partials, SB);
  scan_apply<<<SB, 256, 0, stream>>>(row_cnt, partials, row_start, row_cur, N);
  fill_kernel<<<eb, 256, 0, stream>>>(src, dst, row_cur, src_sorted, E);

  int ab = (N * 64 + 255) / 256;  // one wave per node
  agg_mean64<<<ab, 256, 0, stream>>>(xbf, row_start, row_cnt, src_sorted, A1, N);

  int gb = (N + 127) / 128;
  mfma_gemm<128, true><<<gb, 256, 0, stream>>>(A1, W1, b1, A2, nullptr, N, 256, 128);

  agg_mean128<<<ab, 256, 0, stream>>>(A2, row_start, row_cnt, src_sorted, A2, N);
  mfma_gemm<256, false><<<gb, 256, 0, stream>>>(A2, W2, b2, nullptr, out, N, 128, 0);
}

// Round 5
// 253.571 us; speedup vs baseline: 6.3174x; 1.2177x over previous
//
#include <hip/hip_runtime.h>

#define N_NODES 50000
#define NBUCK 391   // ceil(N_NODES / 128)

typedef __attribute__((ext_vector_type(8))) short short8;
typedef __attribute__((ext_vector_type(4))) float floatx4;

static __device__ __forceinline__ unsigned short f2bf(float f) {
  unsigned int u = __builtin_bit_cast(unsigned int, f);
  u += 0x7fff + ((u >> 16) & 1);          // RNE
  return (unsigned short)(u >> 16);
}
static __device__ __forceinline__ float bf2f(unsigned short s) {
  unsigned int u = ((unsigned int)s) << 16;
  return __builtin_bit_cast(float, u);
}

// ---------------- input casts ----------------

__global__ void cast_x(const float* __restrict__ x, unsigned short* __restrict__ xbf,
                       unsigned short* __restrict__ A1, int total) {
  int i = blockIdx.x * blockDim.x + threadIdx.x;
  if (i >= total) return;
  unsigned short b = f2bf(x[i]);
  xbf[i] = b;
  A1[(size_t)(i >> 6) * 128 + 64 + (i & 63)] = b;
}

__global__ void cast_w(const float* __restrict__ Wl1, const float* __restrict__ Wr1,
                       const float* __restrict__ Wl2, const float* __restrict__ Wr2,
                       unsigned short* __restrict__ W1, unsigned short* __restrict__ W2) {
  int t = blockIdx.x * blockDim.x + threadIdx.x;
  if (t < 128 * 128) {
    int c = t >> 7, k = t & 127;
    W1[t] = f2bf(k < 64 ? Wl1[c * 64 + k] : Wr1[c * 64 + k - 64]);
  } else {
    int t2 = t - 128 * 128;
    if (t2 < 128 * 256) {
      int c = t2 >> 8, k = t2 & 255;
      W2[t2] = f2bf(k < 128 ? Wl2[c * 128 + k] : Wr2[c * 128 + k - 128]);
    }
  }
}

// ---------------- CSR build: count / hierarchical scan / bucketed fill ----------------

__global__ void count_kernel(const int* __restrict__ dst, int* __restrict__ cnt, int E) {
  int i = blockIdx.x * blockDim.x + threadIdx.x;
  if (i < E) atomicAdd(&cnt[dst[i]], 1);
}

__global__ void __launch_bounds__(256) scan_partial(const int* __restrict__ cnt,
    int* __restrict__ partials, int n) {
  int t = threadIdx.x;
  int i0 = blockIdx.x * 512 + t * 2;
  int s = 0;
  if (i0 < n) s += cnt[i0];
  if (i0 + 1 < n) s += cnt[i0 + 1];
  __shared__ int red[4];
#pragma unroll
  for (int off = 32; off; off >>= 1) s += __shfl_down(s, off, 64);
  if ((t & 63) == 0) red[t >> 6] = s;
  __syncthreads();
  if (t == 0) partials[blockIdx.x] = red[0] + red[1] + red[2] + red[3];
}

__global__ void __launch_bounds__(128) scan_offsets(int* __restrict__ partials, int P) {
  __shared__ int tmp[128];
  int t = threadIdx.x;
  int v = (t < P) ? partials[t] : 0;
  tmp[t] = v;
  __syncthreads();
#pragma unroll
  for (int off = 1; off < 128; off <<= 1) {
    int u = (t >= off) ? tmp[t - off] : 0;
    __syncthreads();
    tmp[t] += u;
    __syncthreads();
  }
  if (t < P) partials[t] = tmp[t] - v;
}

// writes row_start; also seeds bucket_cur[b] = row_start[b*128]
__global__ void __launch_bounds__(256) scan_apply(const int* __restrict__ cnt,
    const int* __restrict__ partials, int* __restrict__ row_start,
    int* __restrict__ bucket_cur, int n) {
  __shared__ int tmp[256];
  int t = threadIdx.x;
  int i0 = blockIdx.x * 512 + t * 2;
  int c0 = (i0 < n) ? cnt[i0] : 0;
  int c1 = (i0 + 1 < n) ? cnt[i0 + 1] : 0;
  int s = c0 + c1;
  tmp[t] = s;
  __syncthreads();
#pragma unroll
  for (int off = 1; off < 256; off <<= 1) {
    int u = (t >= off) ? tmp[t - off] : 0;
    __syncthreads();
    tmp[t] += u;
    __syncthreads();
  }
  int ex = tmp[t] - s + partials[blockIdx.x];
  if (i0 < n) {
    row_start[i0] = ex;
    if ((i0 & 127) == 0) bucket_cur[i0 >> 7] = ex;
    if (i0 + 1 < n) row_start[i0 + 1] = ex + c0;
  }
}

// pass 1: bucket edges by dst>>7 with block-batched range reservation.
// packed = (src << 7) | (dst & 127); src < 65536 so this fits 23 bits.
__global__ void __launch_bounds__(1024) bucket_scatter(
    const int* __restrict__ src, const int* __restrict__ dst,
    int* __restrict__ bucket_cur, int* __restrict__ buf1, int E) {
  __shared__ int hist[NBUCK];
  __shared__ int base_s[NBUCK];
  int t = threadIdx.x;
  for (int i = t; i < NBUCK; i += 1024) hist[i] = 0;
  __syncthreads();
  int e0 = blockIdx.x * 4096;
  int sv[4], dv[4], bv[4];
#pragma unroll
  for (int p = 0; p < 4; ++p) {
    int e = e0 + p * 1024 + t;
    if (e < E) {
      sv[p] = src[e];
      dv[p] = dst[e];
      bv[p] = dv[p] >> 7;
      atomicAdd(&hist[bv[p]], 1);
    } else bv[p] = -1;
  }
  __syncthreads();
  for (int i = t; i < NBUCK; i += 1024) {
    int c = hist[i];
    base_s[i] = c > 0 ? atomicAdd(&bucket_cur[i], c) : 0;
  }
  __syncthreads();
  for (int i = t; i < NBUCK; i += 1024) hist[i] = 0;   // reuse as sub-cursor
  __syncthreads();
#pragma unroll
  for (int p = 0; p < 4; ++p) {
    if (bv[p] >= 0) {
      int sub = atomicAdd(&hist[bv[p]], 1);
      buf1[base_s[bv[p]] + sub] = (sv[p] << 7) | (dv[p] & 127);
    }
  }
}

// pass 2: one block per bucket; exact per-node positions via 128 LDS cursors.
// All reads/writes land in the bucket's own contiguous CSR segment (~8KB).
__global__ void __launch_bounds__(256) csr_scatter(
    const int* __restrict__ buf1, const int* __restrict__ row_start,
    int* __restrict__ src_sorted, int n, int E) {
  __shared__ int cur[128];
  int b = blockIdx.x;
  int t = threadIdx.x;
  int node0 = b << 7;
  if (t < 128) {
    int nd = node0 + t;
    cur[t] = nd < n ? row_start[nd] : E;
  }
  __syncthreads();
  int s = row_start[node0];
  int e = (node0 + 128 < n) ? row_start[node0 + 128] : E;
  for (int i = s + t; i < e; i += 256) {
    int packed = buf1[i];
    int pos = atomicAdd(&cur[packed & 127], 1);
    src_sorted[pos] = packed >> 7;
  }
}

// ---------------- gather-reduce mean aggregation (bf16 in/out, fp32 acc) ----------------

__global__ void agg_mean64(const unsigned short* __restrict__ xbf,
    const int* __restrict__ row_start, const int* __restrict__ row_cnt,
    const int* __restrict__ srcs, unsigned short* __restrict__ A1, int n) {
  int wid = (blockIdx.x * blockDim.x + threadIdx.x) >> 6;
  int lane = threadIdx.x & 63;
  if (wid >= n) return;
  int start = row_start[wid];
  int cnt = row_cnt[wid];
  float a0 = 0.f, a1 = 0.f, a2 = 0.f, a3 = 0.f;
  int e = 0;
  for (; e + 4 <= cnt; e += 4) {
    int s0 = srcs[start + e];
    int s1 = srcs[start + e + 1];
    int s2 = srcs[start + e + 2];
    int s3 = srcs[start + e + 3];
    a0 += bf2f(xbf[(size_t)s0 * 64 + lane]);
    a1 += bf2f(xbf[(size_t)s1 * 64 + lane]);
    a2 += bf2f(xbf[(size_t)s2 * 64 + lane]);
    a3 += bf2f(xbf[(size_t)s3 * 64 + lane]);
  }
  for (; e < cnt; ++e) a0 += bf2f(xbf[(size_t)srcs[start + e] * 64 + lane]);
  A1[(size_t)wid * 128 + lane] = f2bf((a0 + a1 + a2 + a3) * (1.0f / (float)max(cnt, 1)));
}

__global__ void agg_mean128(const unsigned short* __restrict__ A2c,
    const int* __restrict__ row_start, const int* __restrict__ row_cnt,
    const int* __restrict__ srcs, unsigned short* __restrict__ A2w, int n) {
  int wid = (blockIdx.x * blockDim.x + threadIdx.x) >> 6;
  int lane = threadIdx.x & 63;
  if (wid >= n) return;
  int start = row_start[wid];
  int cnt = row_cnt[wid];
  float ax = 0.f, ay = 0.f, bx = 0.f, by = 0.f;
  float cx = 0.f, cy = 0.f, dx = 0.f, dy = 0.f;
  int e = 0;
  for (; e + 4 <= cnt; e += 4) {
    int s0 = srcs[start + e];
    int s1 = srcs[start + e + 1];
    int s2 = srcs[start + e + 2];
    int s3 = srcs[start + e + 3];
    unsigned int u0 = *(const unsigned int*)(A2c + (size_t)s0 * 256 + 128 + lane * 2);
    unsigned int u1 = *(const unsigned int*)(A2c + (size_t)s1 * 256 + 128 + lane * 2);
    unsigned int u2 = *(const unsigned int*)(A2c + (size_t)s2 * 256 + 128 + lane * 2);
    unsigned int u3 = *(const unsigned int*)(A2c + (size_t)s3 * 256 + 128 + lane * 2);
    ax += bf2f((unsigned short)u0); ay += bf2f((unsigned short)(u0 >> 16));
    bx += bf2f((unsigned short)u1); by += bf2f((unsigned short)(u1 >> 16));
    cx += bf2f((unsigned short)u2); cy += bf2f((unsigned short)(u2 >> 16));
    dx += bf2f((unsigned short)u3); dy += bf2f((unsigned short)(u3 >> 16));
  }
  for (; e < cnt; ++e) {
    unsigned int u0 = *(const unsigned int*)(A2c + (size_t)srcs[start + e] * 256 + 128 + lane * 2);
    ax += bf2f((unsigned short)u0); ay += bf2f((unsigned short)(u0 >> 16));
  }
  float inv = 1.0f / (float)max(cnt, 1);
  unsigned int packed = (unsigned int)f2bf((ax + bx + cx + dx) * inv)
                      | ((unsigned int)f2bf((ay + by + cy + dy) * inv) << 16);
  *(unsigned int*)(A2w + (size_t)wid * 256 + lane * 2) = packed;
}

// ---------------- MFMA GEMM: out = relu(A'(n,KP) x W'(128,KP)^T + bias) ----------------

template<int KP, bool BF_OUT>
__global__ void __launch_bounds__(256) mfma_gemm(
    const unsigned short* __restrict__ A, const unsigned short* __restrict__ W,
    const float* __restrict__ bias, unsigned short* __restrict__ outb,
    float* __restrict__ outf, int n, int ostride, int ocol) {
  const int lane = threadIdx.x & 63;
  const int wv = threadIdx.x >> 6;
  const int m = lane & 15;
  const int q = lane >> 4;
  const int r0 = blockIdx.x * 128 + wv * 32;

  floatx4 acc[2][8];
#pragma unroll
  for (int rt = 0; rt < 2; ++rt)
#pragma unroll
    for (int ct = 0; ct < 8; ++ct) acc[rt][ct] = (floatx4){0.f, 0.f, 0.f, 0.f};

  int ra = r0 + m;      if (ra > n - 1) ra = n - 1;
  int rb = r0 + 16 + m; if (rb > n - 1) rb = n - 1;
  const unsigned short* Arow0 = A + (size_t)ra * KP + q * 8;
  const unsigned short* Arow1 = A + (size_t)rb * KP + q * 8;
  const unsigned short* Wrow  = W + (size_t)m * KP + q * 8;

#pragma unroll 1
  for (int kc = 0; kc < KP / 32; ++kc) {
    short8 a0 = *(const short8*)(Arow0 + kc * 32);
    short8 a1 = *(const short8*)(Arow1 + kc * 32);
#pragma unroll
    for (int ct = 0; ct < 8; ++ct) {
      short8 wf = *(const short8*)(Wrow + (size_t)ct * 16 * KP + kc * 32);
      acc[0][ct] = __builtin_amdgcn_mfma_f32_16x16x32_bf16(a0, wf, acc[0][ct], 0, 0, 0);
      acc[1][ct] = __builtin_amdgcn_mfma_f32_16x16x32_bf16(a1, wf, acc[1][ct], 0, 0, 0);
    }
  }

  float bv[8];
#pragma unroll
  for (int ct = 0; ct < 8; ++ct) bv[ct] = bias[ct * 16 + m];

#pragma unroll
  for (int rt = 0; rt < 2; ++rt) {
#pragma unroll
    for (int j = 0; j < 4; ++j) {
      int row = r0 + rt * 16 + q * 4 + j;
      if (row < n) {
#pragma unroll
        for (int ct = 0; ct < 8; ++ct) {
          float v = acc[rt][ct][j] + bv[ct];
          v = v > 0.f ? v : 0.f;
          int col = ct * 16 + m;
          if (BF_OUT) outb[(size_t)row * ostride + ocol + col] = f2bf(v);
          else        outf[(size_t)row * ostride + col] = v;
        }
      }
    }
  }
}

// ---------------- launch ----------------

extern "C" void kernel_launch(void* const* d_in, const int* in_sizes, int n_in,
                              void* d_out, int out_size, void* d_ws, size_t ws_size,
                              hipStream_t stream) {
  const int N = N_NODES;
  const int E = in_sizes[1] / 2;
  const float* x   = (const float*)d_in[0];
  const int*   src = (const int*)d_in[1];
  const int*   dst = src + E;
  const float* Wl1 = (const float*)d_in[2];
  const float* Wr1 = (const float*)d_in[3];
  const float* b1  = (const float*)d_in[4];
  const float* Wl2 = (const float*)d_in[5];
  const float* Wr2 = (const float*)d_in[6];
  const float* b2  = (const float*)d_in[7];
  float* out = (float*)d_out;

  // workspace (~52 MB)
  unsigned short* A1  = (unsigned short*)d_ws;        // N*128 bf16
  unsigned short* A2  = A1 + (size_t)N * 128;         // N*256 bf16
  unsigned short* xbf = A2 + (size_t)N * 256;         // N*64 bf16
  unsigned short* W1  = xbf + (size_t)N * 64;         // 128*128
  unsigned short* W2  = W1 + 128 * 128;               // 128*256
  int* row_cnt    = (int*)(W2 + 128 * 256);
  int* row_start  = row_cnt + N;
  int* bucket_cur = row_start + N;                    // NBUCK ints
  int* src_sorted = bucket_cur + NBUCK;               // E ints
  int* buf1       = src_sorted + E;                   // E ints
  int* partials   = buf1 + E;                         // 128 ints

  const int SB = (N + 511) / 512;

  hipMemsetAsync(row_cnt, 0, N * sizeof(int), stream);
  cast_x<<<(N * 64 + 255) / 256, 256, 0, stream>>>(x, xbf, A1, N * 64);
  cast_w<<<(128 * 128 + 128 * 256 + 255) / 256, 256, 0, stream>>>(Wl1, Wr1, Wl2, Wr2, W1, W2);

  int eb = (E + 255) / 256;
  count_kernel<<<eb, 256, 0, stream>>>(dst, row_cnt, E);
  scan_partial<<<SB, 256, 0, stream>>>(row_cnt, partials, N);
  scan_offsets<<<1, 128, 0, stream>>>(partials, SB);
  scan_apply<<<SB, 256, 0, stream>>>(row_cnt, partials, row_start, bucket_cur, N);
  bucket_scatter<<<(E + 4095) / 4096, 1024, 0, stream>>>(src, dst, bucket_cur, buf1, E);
  csr_scatter<<<NBUCK, 256, 0, stream>>>(buf1, row_start, src_sorted, N, E);

  int ab = (N * 64 + 255) / 256;  // one wave per node
  agg_mean64<<<ab, 256, 0, stream>>>(xbf, row_start, row_cnt, src_sorted, A1, N);

  int gb = (N + 127) / 128;
  mfma_gemm<128, true><<<gb, 256, 0, stream>>>(A1, W1, b1, A2, nullptr, N, 256, 128);

  agg_mean128<<<ab, 256, 0, stream>>>(A2, row_start, row_cnt, src_sorted, A2, N);
  mfma_gemm<256, false><<<gb, 256, 0, stream>>>(A2, W2, b2, nullptr, out, N, 128, 0);
}